// Round 1
// baseline (838.405 us; speedup 1.0000x reference)
//
#include <hip/hip_runtime.h>
#include <hip/hip_bf16.h>
#include <math.h>

#define N_NODES 20000
#define N_EDGES 320000
#define F_IN    127
#define D_HID   512
#define N_HEADS 4
#define HC      128
#define N_OUT   256
#define ETOT    (N_EDGES + N_NODES)

// ---------------- CSR build ----------------
__global__ void k_init(int* __restrict__ counts, float* __restrict__ stats) {
  int i = blockIdx.x * blockDim.x + threadIdx.x;
  if (i < N_NODES) counts[i] = 1;   // self loop pre-counted
  if (i < 2048) stats[i] = 0.f;     // both layers' colsum/colsumsq
}

__global__ void k_hist(const int* __restrict__ ei, int* __restrict__ counts) {
  int e = blockIdx.x * blockDim.x + threadIdx.x;
  if (e < N_EDGES) atomicAdd(&counts[ei[N_EDGES + e]], 1);
}

__global__ __launch_bounds__(1024) void k_scan(const int* __restrict__ counts,
                                               int* __restrict__ row_start) {
  __shared__ int part[1024];
  const int per = (N_NODES + 1023) / 1024;   // 20
  int t = threadIdx.x;
  int base = t * per;
  int s = 0;
  for (int i = 0; i < per; ++i) {
    int idx = base + i;
    if (idx < N_NODES) s += counts[idx];
  }
  part[t] = s;
  __syncthreads();
  for (int off = 1; off < 1024; off <<= 1) {
    int v = (t >= off) ? part[t - off] : 0;
    __syncthreads();
    part[t] += v;
    __syncthreads();
  }
  int run = part[t] - s;                      // exclusive prefix of this chunk
  for (int i = 0; i < per; ++i) {
    int idx = base + i;
    if (idx < N_NODES) { row_start[idx] = run; run += counts[idx]; }
  }
  if (t == 1023) row_start[N_NODES] = part[1023];
}

__global__ void k_self(const int* __restrict__ row_start, int* __restrict__ wcur,
                       int* __restrict__ srcs) {
  int i = blockIdx.x * blockDim.x + threadIdx.x;
  if (i < N_NODES) { int p = row_start[i]; srcs[p] = i; wcur[i] = p + 1; }
}

__global__ void k_scatter(const int* __restrict__ ei, int* __restrict__ wcur,
                          int* __restrict__ srcs) {
  int e = blockIdx.x * blockDim.x + threadIdx.x;
  if (e < N_EDGES) {
    int s = ei[e], d = ei[N_EDGES + e];
    int p = atomicAdd(&wcur[d], 1);
    srcs[p] = s;
  }
}

// ---------------- concat x = [X | pos_emb] ----------------
__global__ void k_concat(const float* __restrict__ X, const float* __restrict__ pos,
                         float* __restrict__ x) {
  int i = blockIdx.x * blockDim.x + threadIdx.x;
  if (i >= N_NODES * 128) return;
  int n = i >> 7, k = i & 127;
  x[i] = (k < F_IN) ? X[n * F_IN + k] : pos[n];
}

// ---------------- fp32 tiled GEMM: C[M,Nc] = A[M,K] @ B[K,Nc] (+bias) ----------------
// 64x64 tile, 256 threads, 4x4 microtile, A transposed in LDS.
__global__ __launch_bounds__(256) void k_gemm(
    const float* __restrict__ A, const float* __restrict__ B,
    const float* __restrict__ bias, float* __restrict__ C,
    int M, int Nc, int K)
{
  __shared__ float As[16][64];   // [k][m]
  __shared__ float Bs[16][64];   // [k][n]
  int t = threadIdx.x;
  int tx = t & 15, ty = t >> 4;
  int bm = blockIdx.y, bn = blockIdx.x;
  int row0 = bm * 64 + ty * 4;
  int col0 = bn * 64 + tx * 4;
  int ar = t >> 2, ac = (t & 3) * 4;          // A: row ar (0..63), k-offset ac
  int br = t >> 4, bc = (t & 15) * 4;         // B: k-row br (0..15), col bc
  int Arow = bm * 64 + ar;
  bool a_ok = (Arow < M);
  const float* Aptr = A + (size_t)Arow * K + ac;
  const float* Bptr = B + (size_t)br * Nc + bn * 64 + bc;
  float acc[4][4] = {};
  for (int k0 = 0; k0 < K; k0 += 16) {
    float4 av = a_ok ? *(const float4*)(Aptr + k0) : make_float4(0.f, 0.f, 0.f, 0.f);
    float4 bv = *(const float4*)(Bptr + (size_t)k0 * Nc);
    __syncthreads();
    As[ac + 0][ar] = av.x; As[ac + 1][ar] = av.y;
    As[ac + 2][ar] = av.z; As[ac + 3][ar] = av.w;
    *(float4*)&Bs[br][bc] = bv;
    __syncthreads();
#pragma unroll
    for (int k = 0; k < 16; ++k) {
      float4 a4 = *(const float4*)&As[k][ty * 4];
      float4 b4 = *(const float4*)&Bs[k][tx * 4];
      float aa[4] = {a4.x, a4.y, a4.z, a4.w};
      float bb[4] = {b4.x, b4.y, b4.z, b4.w};
#pragma unroll
      for (int i = 0; i < 4; ++i)
#pragma unroll
        for (int j = 0; j < 4; ++j) acc[i][j] = fmaf(aa[i], bb[j], acc[i][j]);
    }
  }
#pragma unroll
  for (int i = 0; i < 4; ++i) {
    int r = row0 + i;
    if (r < M) {
      float4 o = make_float4(acc[i][0], acc[i][1], acc[i][2], acc[i][3]);
      if (bias) {
        o.x += bias[col0 + 0]; o.y += bias[col0 + 1];
        o.z += bias[col0 + 2]; o.w += bias[col0 + 3];
      }
      *(float4*)&C[(size_t)r * Nc + col0] = o;
    }
  }
}

// ---------------- attention logits vectors: al_s/al_d [N,4] ----------------
__global__ __launch_bounds__(512) void k_al(
    const float* __restrict__ xl, const float* __restrict__ a_src,
    const float* __restrict__ a_dst, float* __restrict__ al_s, float* __restrict__ al_d)
{
  int n = blockIdx.x, t = threadIdx.x;
  float v = xl[(size_t)n * 512 + t];
  float ps = v * a_src[t];
  float pd = v * a_dst[t];
#pragma unroll
  for (int off = 32; off; off >>= 1) { ps += __shfl_down(ps, off); pd += __shfl_down(pd, off); }
  __shared__ float red[8][2];
  int w = t >> 6;
  if ((t & 63) == 0) { red[w][0] = ps; red[w][1] = pd; }
  __syncthreads();
  if (t < 4) {   // head t spans waves 2t, 2t+1
    al_s[n * 4 + t] = red[2 * t][0] + red[2 * t + 1][0];
    al_d[n * 4 + t] = red[2 * t][1] + red[2 * t + 1][1];
  }
}

// ---------------- GAT aggregate: one block per dst node ----------------
__global__ __launch_bounds__(512) void k_agg(
    const float* __restrict__ xl, const float* __restrict__ al_s,
    const float* __restrict__ al_d, const int* __restrict__ row_start,
    const int* __restrict__ srcs, const float* __restrict__ bias,
    float* __restrict__ out)
{
  int n = blockIdx.x, t = threadIdx.x;
  int h = t >> 7;
  __shared__ float s_max[4], s_rinv[4];
  __shared__ float s_alpha[128][4];
  __shared__ int   s_src[128];
  int rs = row_start[n], re = row_start[n + 1];
  int deg = re - rs;   // >= 1 (self loop)

  if (t < 64) {        // wave 0: online softmax max & denom per head
    float lm[4], ls[4];
#pragma unroll
    for (int hh = 0; hh < 4; ++hh) { lm[hh] = -1e30f; ls[hh] = 0.f; }
    float dd[4] = {al_d[n * 4 + 0], al_d[n * 4 + 1], al_d[n * 4 + 2], al_d[n * 4 + 3]};
    for (int i = t; i < deg; i += 64) {
      int s = srcs[rs + i];
#pragma unroll
      for (int hh = 0; hh < 4; ++hh) {
        float l = al_s[s * 4 + hh] + dd[hh];
        l = (l >= 0.f) ? l : 0.2f * l;             // attention LeakyReLU 0.2
        if (l > lm[hh]) { ls[hh] = ls[hh] * __expf(lm[hh] - l) + 1.f; lm[hh] = l; }
        else            { ls[hh] += __expf(l - lm[hh]); }
      }
    }
#pragma unroll
    for (int off = 32; off; off >>= 1) {
#pragma unroll
      for (int hh = 0; hh < 4; ++hh) {
        float om = __shfl_xor(lm[hh], off);
        float os = __shfl_xor(ls[hh], off);
        float M = fmaxf(lm[hh], om);
        ls[hh] = ls[hh] * __expf(lm[hh] - M) + os * __expf(om - M);
        lm[hh] = M;
      }
    }
    if (t == 0) {
#pragma unroll
      for (int hh = 0; hh < 4; ++hh) { s_max[hh] = lm[hh]; s_rinv[hh] = 1.f / (ls[hh] + 1e-16f); }
    }
  }
  __syncthreads();

  float acc = 0.f;
  for (int c0 = 0; c0 < deg; c0 += 128) {
    int csz = min(128, deg - c0);
    if (t < csz * 4) {               // recompute alpha for this chunk into LDS
      int i = t >> 2, hh = t & 3;
      int s = srcs[rs + c0 + i];
      if (hh == 0) s_src[i] = s;
      float l = al_s[s * 4 + hh] + al_d[n * 4 + hh];
      l = (l >= 0.f) ? l : 0.2f * l;
      s_alpha[i][hh] = __expf(l - s_max[hh]) * s_rinv[hh];
    }
    __syncthreads();
    const float* xp = xl + t;
#pragma unroll 4
    for (int i = 0; i < csz; ++i) {
      acc = fmaf(xp[(size_t)s_src[i] * 512], s_alpha[i][h], acc);
    }
    __syncthreads();
  }
  out[(size_t)n * 512 + t] = acc + bias[t];
}

// ---------------- column stats (sum, sumsq) ----------------
__global__ __launch_bounds__(512) void k_stats(const float* __restrict__ hdat,
                                               float* __restrict__ sums) {
  int t = threadIdx.x;
  int r0 = blockIdx.x * 64;
  int r1 = min(r0 + 64, N_NODES);
  float s = 0.f, q = 0.f;
  for (int r = r0; r < r1; ++r) {
    float v = hdat[(size_t)r * 512 + t];
    s += v; q = fmaf(v, v, q);
  }
  atomicAdd(&sums[t], s);
  atomicAdd(&sums[512 + t], q);
}

// ---------------- BN + LeakyReLU(0.01) [in-place], optional residual ----------------
__global__ void k_bn_act(float* __restrict__ hdat, const float* __restrict__ stats,
                         const float* __restrict__ g, const float* __restrict__ b) {
  int i = blockIdx.x * blockDim.x + threadIdx.x;
  if (i >= N_NODES * 512) return;
  int c = i & 511;
  const float invN = 1.f / N_NODES;
  float mu = stats[c] * invN;
  float var = stats[512 + c] * invN - mu * mu;
  float y = (hdat[i] - mu) * rsqrtf(var + 1e-5f) * g[c] + b[c];
  hdat[i] = (y >= 0.f) ? y : 0.01f * y;
}

__global__ void k_bn_act_res(float* __restrict__ hdat, const float* __restrict__ hprev,
                             const float* __restrict__ stats,
                             const float* __restrict__ g, const float* __restrict__ b) {
  int i = blockIdx.x * blockDim.x + threadIdx.x;
  if (i >= N_NODES * 512) return;
  int c = i & 511;
  const float invN = 1.f / N_NODES;
  float mu = stats[c] * invN;
  float var = stats[512 + c] * invN - mu * mu;
  float y = (hdat[i] - mu) * rsqrtf(var + 1e-5f) * g[c] + b[c];
  y = (y >= 0.f) ? y : 0.01f * y;
  hdat[i] = y + hprev[i];
}

extern "C" void kernel_launch(void* const* d_in, const int* in_sizes, int n_in,
                              void* d_out, int out_size, void* d_ws, size_t ws_size,
                              hipStream_t stream) {
  const float* X      = (const float*)d_in[0];
  const int*   ei     = (const int*)d_in[1];
  const float* pos    = (const float*)d_in[3];
  const float* W1     = (const float*)d_in[4];
  const float* a_src1 = (const float*)d_in[5];
  const float* a_dst1 = (const float*)d_in[6];
  const float* b1     = (const float*)d_in[7];
  const float* W2     = (const float*)d_in[8];
  const float* a_src2 = (const float*)d_in[9];
  const float* a_dst2 = (const float*)d_in[10];
  const float* b2     = (const float*)d_in[11];
  const float* bn1_g  = (const float*)d_in[12];
  const float* bn1_b  = (const float*)d_in[13];
  const float* bn2_g  = (const float*)d_in[14];
  const float* bn2_b  = (const float*)d_in[15];
  const float* out_W  = (const float*)d_in[18];
  const float* out_b  = (const float*)d_in[19];
  float* out = (float*)d_out;

  float* ws = (float*)d_ws;
  size_t o = 0;
  float* x     = ws + o; o += (size_t)N_NODES * 128;   // 10.2 MB
  float* xl    = ws + o; o += (size_t)N_NODES * 512;   // 41 MB  (GEMM out, both layers)
  float* aggA  = ws + o; o += (size_t)N_NODES * 512;   // 41 MB  (layer1 agg -> h1)
  float* aggB  = ws + o; o += (size_t)N_NODES * 512;   // 41 MB  (layer2 agg -> h2)
  float* alS   = ws + o; o += (size_t)N_NODES * 4;
  float* alD   = ws + o; o += (size_t)N_NODES * 4;
  float* stats = ws + o; o += 2048;                    // [layer1 1024 | layer2 1024]
  int* ip = (int*)(ws + o);
  int* counts    = ip; ip += N_NODES;
  int* row_start = ip; ip += N_NODES + 1;
  int* wcur      = ip; ip += N_NODES;
  int* srcs      = ip; ip += ETOT;

  // CSR by dst (self loops included)
  k_init   <<<(N_NODES + 255) / 256, 256, 0, stream>>>(counts, stats);
  k_hist   <<<(N_EDGES + 255) / 256, 256, 0, stream>>>(ei, counts);
  k_scan   <<<1, 1024, 0, stream>>>(counts, row_start);
  k_self   <<<(N_NODES + 255) / 256, 256, 0, stream>>>(row_start, wcur, srcs);
  k_scatter<<<(N_EDGES + 255) / 256, 256, 0, stream>>>(ei, wcur, srcs);
  k_concat <<<(N_NODES * 128 + 255) / 256, 256, 0, stream>>>(X, pos, x);

  dim3 gA(512 / 64, (N_NODES + 63) / 64);
  // ---- layer 1 ----
  k_gemm<<<gA, 256, 0, stream>>>(x, W1, nullptr, xl, N_NODES, 512, 128);
  k_al  <<<N_NODES, 512, 0, stream>>>(xl, a_src1, a_dst1, alS, alD);
  k_agg <<<N_NODES, 512, 0, stream>>>(xl, alS, alD, row_start, srcs, b1, aggA);
  k_stats<<<(N_NODES + 63) / 64, 512, 0, stream>>>(aggA, stats);
  k_bn_act<<<(N_NODES * 512 + 255) / 256, 256, 0, stream>>>(aggA, stats, bn1_g, bn1_b);
  // ---- layer 2 ----
  k_gemm<<<gA, 256, 0, stream>>>(aggA, W2, nullptr, xl, N_NODES, 512, 512);
  k_al  <<<N_NODES, 512, 0, stream>>>(xl, a_src2, a_dst2, alS, alD);
  k_agg <<<N_NODES, 512, 0, stream>>>(xl, alS, alD, row_start, srcs, b2, aggB);
  k_stats<<<(N_NODES + 63) / 64, 512, 0, stream>>>(aggB, stats + 1024);
  k_bn_act_res<<<(N_NODES * 512 + 255) / 256, 256, 0, stream>>>(aggB, aggA, stats + 1024, bn2_g, bn2_b);
  // ---- output projection ----
  dim3 gO(256 / 64, (N_NODES + 63) / 64);
  k_gemm<<<gO, 256, 0, stream>>>(aggB, out_W, out_b, out, N_NODES, 256, 512);
}

// Round 2
// 650.671 us; speedup vs baseline: 1.2885x; 1.2885x over previous
//
#include <hip/hip_runtime.h>
#include <hip/hip_bf16.h>
#include <math.h>

#define N_NODES 20000
#define N_EDGES 320000
#define F_IN    127
#define ETOT    (N_EDGES + N_NODES)

typedef __attribute__((ext_vector_type(8))) short short8;
typedef __attribute__((ext_vector_type(4))) float f32x4;

__device__ inline unsigned short f2bf(float f) {
  union { float f; unsigned int u; } v; v.f = f;
  unsigned int u = v.u;
  unsigned int r = (u + 0x7fffu + ((u >> 16) & 1u)) >> 16;
  return (unsigned short)r;
}

// ---------------- CSR build ----------------
__global__ void k_init(int* __restrict__ counts, float* __restrict__ stats) {
  int i = blockIdx.x * blockDim.x + threadIdx.x;
  if (i < N_NODES) counts[i] = 1;   // self loop pre-counted
  if (i < 2048) stats[i] = 0.f;
}

__global__ void k_hist(const int* __restrict__ ei, int* __restrict__ counts) {
  int e = blockIdx.x * blockDim.x + threadIdx.x;
  if (e < N_EDGES) atomicAdd(&counts[ei[N_EDGES + e]], 1);
}

__global__ __launch_bounds__(1024) void k_scan(const int* __restrict__ counts,
                                               int* __restrict__ row_start) {
  __shared__ int part[1024];
  const int per = (N_NODES + 1023) / 1024;
  int t = threadIdx.x;
  int base = t * per;
  int s = 0;
  for (int i = 0; i < per; ++i) {
    int idx = base + i;
    if (idx < N_NODES) s += counts[idx];
  }
  part[t] = s;
  __syncthreads();
  for (int off = 1; off < 1024; off <<= 1) {
    int v = (t >= off) ? part[t - off] : 0;
    __syncthreads();
    part[t] += v;
    __syncthreads();
  }
  int run = part[t] - s;
  for (int i = 0; i < per; ++i) {
    int idx = base + i;
    if (idx < N_NODES) { row_start[idx] = run; run += counts[idx]; }
  }
  if (t == 1023) row_start[N_NODES] = part[1023];
}

__global__ void k_self(const int* __restrict__ row_start, int* __restrict__ wcur,
                       int* __restrict__ srcs) {
  int i = blockIdx.x * blockDim.x + threadIdx.x;
  if (i < N_NODES) { int p = row_start[i]; srcs[p] = i; wcur[i] = p + 1; }
}

__global__ void k_scatter(const int* __restrict__ ei, int* __restrict__ wcur,
                          int* __restrict__ srcs) {
  int e = blockIdx.x * blockDim.x + threadIdx.x;
  if (e < N_EDGES) {
    int s = ei[e], d = ei[N_EDGES + e];
    int p = atomicAdd(&wcur[d], 1);
    srcs[p] = s;
  }
}

// ---------------- concat x = [X | pos_emb] -> bf16 ----------------
__global__ void k_concat(const float* __restrict__ X, const float* __restrict__ pos,
                         unsigned short* __restrict__ xbf) {
  int i = blockIdx.x * blockDim.x + threadIdx.x;
  if (i >= N_NODES * 128) return;
  int n = i >> 7, k = i & 127;
  xbf[i] = f2bf((k < F_IN) ? X[n * F_IN + k] : pos[n]);
}

// ---------------- weights cast + transpose (bf16, B^T layout) ----------------
__global__ void k_prep_w(const float* __restrict__ W1, const float* __restrict__ W2,
                         const float* __restrict__ oW,
                         unsigned short* __restrict__ W1t, unsigned short* __restrict__ W2t,
                         unsigned short* __restrict__ oWt) {
  int i = blockIdx.x * blockDim.x + threadIdx.x;
  if (i < 128 * 512) { int r = i >> 9, c = i & 511; W1t[c * 128 + r] = f2bf(W1[i]); }
  if (i < 512 * 512) { int r = i >> 9, c = i & 511; W2t[c * 512 + r] = f2bf(W2[i]); }
  if (i < 512 * 256) { int r = i >> 8, c = i & 255; oWt[c * 512 + r] = f2bf(oW[i]); }
}

// ---------------- bf16 MFMA GEMM: C[M,Nc] = A[M,K](bf16) @ Bt[Nc,K](bf16)^T ----------------
// 128x128 tile, 256 thr (4 waves, 2x2), each wave 64x64 = 4x4 MFMA 16x16x32.
__global__ __launch_bounds__(256) void k_mgemm(
    const unsigned short* __restrict__ A, const unsigned short* __restrict__ Bt,
    const float* __restrict__ bias, float* __restrict__ C,
    int M, int Nc, int K)
{
  __shared__ unsigned short As[128 * 32];
  __shared__ unsigned short Bs[128 * 32];
  int t = threadIdx.x;
  int w = t >> 6, l = t & 63;
  int wr = w >> 1, wc = w & 1;
  int lane15 = l & 15, kq = l >> 4;
  int m0 = blockIdx.y * 128, n0 = blockIdx.x * 128;
  f32x4 acc[4][4] = {};

  int cA = 2 * w;                 // this wave stages chunks cA, cA+1 of A and of B
  int rowA0 = 16 * cA + (l >> 2); // row within 128-tile for chunk cA
  int koff = (l & 3) * 8;         // k element offset within 32-k slab

  for (int k0 = 0; k0 < K; k0 += 32) {
    __syncthreads();              // prior reads done before overwrite
#pragma unroll
    for (int cc = 0; cc < 2; ++cc) {
      int c = cA + cc;
      int row = rowA0 + 16 * cc;
      const unsigned short* g = A + (size_t)min(m0 + row, M - 1) * K + k0 + koff;
      __builtin_amdgcn_global_load_lds(
          (const __attribute__((address_space(1))) unsigned int*)g,
          (__attribute__((address_space(3))) unsigned int*)&As[c * 512], 16, 0, 0);
      const unsigned short* gb = Bt + (size_t)(n0 + row) * K + k0 + koff;
      __builtin_amdgcn_global_load_lds(
          (const __attribute__((address_space(1))) unsigned int*)gb,
          (__attribute__((address_space(3))) unsigned int*)&Bs[c * 512], 16, 0, 0);
    }
    __syncthreads();
    short8 a[4], b[4];
#pragma unroll
    for (int i = 0; i < 4; ++i)
      a[i] = *(const short8*)&As[(wr * 64 + i * 16 + lane15) * 32 + kq * 8];
#pragma unroll
    for (int j = 0; j < 4; ++j)
      b[j] = *(const short8*)&Bs[(wc * 64 + j * 16 + lane15) * 32 + kq * 8];
#pragma unroll
    for (int i = 0; i < 4; ++i)
#pragma unroll
      for (int j = 0; j < 4; ++j)
        acc[i][j] = __builtin_amdgcn_mfma_f32_16x16x32_bf16(a[i], b[j], acc[i][j], 0, 0, 0);
  }
  // epilogue: C/D layout col=lane&15, row=(lane>>4)*4+reg
#pragma unroll
  for (int i = 0; i < 4; ++i) {
#pragma unroll
    for (int j = 0; j < 4; ++j) {
      int col = n0 + wc * 64 + j * 16 + lane15;
      float bv = bias ? bias[col] : 0.f;
#pragma unroll
      for (int r = 0; r < 4; ++r) {
        int row = m0 + wr * 64 + i * 16 + kq * 4 + r;
        if (row < M) C[(size_t)row * Nc + col] = acc[i][j][r] + bv;
      }
    }
  }
}

// ---------------- attention logits vectors: al_s/al_d [N,4] ----------------
__global__ __launch_bounds__(512) void k_al(
    const float* __restrict__ xl, const float* __restrict__ a_src,
    const float* __restrict__ a_dst, float* __restrict__ al_s, float* __restrict__ al_d)
{
  int n = blockIdx.x, t = threadIdx.x;
  float v = xl[(size_t)n * 512 + t];
  float ps = v * a_src[t];
  float pd = v * a_dst[t];
#pragma unroll
  for (int off = 32; off; off >>= 1) { ps += __shfl_down(ps, off); pd += __shfl_down(pd, off); }
  __shared__ float red[8][2];
  int w = t >> 6;
  if ((t & 63) == 0) { red[w][0] = ps; red[w][1] = pd; }
  __syncthreads();
  if (t < 4) {
    al_s[n * 4 + t] = red[2 * t][0] + red[2 * t + 1][0];
    al_d[n * 4 + t] = red[2 * t][1] + red[2 * t + 1][1];
  }
}

// ---------------- GAT aggregate: one block per dst node ----------------
__global__ __launch_bounds__(512) void k_agg(
    const float* __restrict__ xl, const float* __restrict__ al_s,
    const float* __restrict__ al_d, const int* __restrict__ row_start,
    const int* __restrict__ srcs, const float* __restrict__ bias,
    float* __restrict__ out)
{
  int n = blockIdx.x, t = threadIdx.x;
  int h = t >> 7;
  __shared__ float s_max[4], s_rinv[4];
  __shared__ float s_alpha[128][4];
  __shared__ int   s_src[128];
  int rs = row_start[n], re = row_start[n + 1];
  int deg = re - rs;

  if (t < 64) {
    float lm[4], ls[4];
#pragma unroll
    for (int hh = 0; hh < 4; ++hh) { lm[hh] = -1e30f; ls[hh] = 0.f; }
    float dd[4] = {al_d[n * 4 + 0], al_d[n * 4 + 1], al_d[n * 4 + 2], al_d[n * 4 + 3]};
    for (int i = t; i < deg; i += 64) {
      int s = srcs[rs + i];
#pragma unroll
      for (int hh = 0; hh < 4; ++hh) {
        float l = al_s[s * 4 + hh] + dd[hh];
        l = (l >= 0.f) ? l : 0.2f * l;
        if (l > lm[hh]) { ls[hh] = ls[hh] * __expf(lm[hh] - l) + 1.f; lm[hh] = l; }
        else            { ls[hh] += __expf(l - lm[hh]); }
      }
    }
#pragma unroll
    for (int off = 32; off; off >>= 1) {
#pragma unroll
      for (int hh = 0; hh < 4; ++hh) {
        float om = __shfl_xor(lm[hh], off);
        float os = __shfl_xor(ls[hh], off);
        float M = fmaxf(lm[hh], om);
        ls[hh] = ls[hh] * __expf(lm[hh] - M) + os * __expf(om - M);
        lm[hh] = M;
      }
    }
    if (t == 0) {
#pragma unroll
      for (int hh = 0; hh < 4; ++hh) { s_max[hh] = lm[hh]; s_rinv[hh] = 1.f / (ls[hh] + 1e-16f); }
    }
  }
  __syncthreads();

  float acc = 0.f;
  for (int c0 = 0; c0 < deg; c0 += 128) {
    int csz = min(128, deg - c0);
    if (t < csz * 4) {
      int i = t >> 2, hh = t & 3;
      int s = srcs[rs + c0 + i];
      if (hh == 0) s_src[i] = s;
      float l = al_s[s * 4 + hh] + al_d[n * 4 + hh];
      l = (l >= 0.f) ? l : 0.2f * l;
      s_alpha[i][hh] = __expf(l - s_max[hh]) * s_rinv[hh];
    }
    __syncthreads();
    const float* xp = xl + t;
#pragma unroll 4
    for (int i = 0; i < csz; ++i) {
      acc = fmaf(xp[(size_t)s_src[i] * 512], s_alpha[i][h], acc);
    }
    __syncthreads();
  }
  out[(size_t)n * 512 + t] = acc + bias[t];
}

// ---------------- column stats (sum, sumsq) ----------------
__global__ __launch_bounds__(512) void k_stats(const float* __restrict__ hdat,
                                               float* __restrict__ sums) {
  int t = threadIdx.x;
  int r0 = blockIdx.x * 64;
  int r1 = min(r0 + 64, N_NODES);
  float s = 0.f, q = 0.f;
  for (int r = r0; r < r1; ++r) {
    float v = hdat[(size_t)r * 512 + t];
    s += v; q = fmaf(v, v, q);
  }
  atomicAdd(&sums[t], s);
  atomicAdd(&sums[512 + t], q);
}

// ---------------- BN + LeakyReLU(0.01); fp32 in-place + bf16 copy ----------------
__global__ void k_bn_act(float* __restrict__ hdat, unsigned short* __restrict__ hbf,
                         const float* __restrict__ stats,
                         const float* __restrict__ g, const float* __restrict__ b) {
  int i = blockIdx.x * blockDim.x + threadIdx.x;
  if (i >= N_NODES * 512) return;
  int c = i & 511;
  const float invN = 1.f / N_NODES;
  float mu = stats[c] * invN;
  float var = stats[512 + c] * invN - mu * mu;
  float y = (hdat[i] - mu) * rsqrtf(var + 1e-5f) * g[c] + b[c];
  y = (y >= 0.f) ? y : 0.01f * y;
  hdat[i] = y;
  hbf[i] = f2bf(y);
}

// BN + act + residual -> bf16 only (feeds final projection)
__global__ void k_bn_act_res(const float* __restrict__ hdat, const float* __restrict__ hprev,
                             unsigned short* __restrict__ hbf,
                             const float* __restrict__ stats,
                             const float* __restrict__ g, const float* __restrict__ b) {
  int i = blockIdx.x * blockDim.x + threadIdx.x;
  if (i >= N_NODES * 512) return;
  int c = i & 511;
  const float invN = 1.f / N_NODES;
  float mu = stats[c] * invN;
  float var = stats[512 + c] * invN - mu * mu;
  float y = (hdat[i] - mu) * rsqrtf(var + 1e-5f) * g[c] + b[c];
  y = (y >= 0.f) ? y : 0.01f * y;
  hbf[i] = f2bf(y + hprev[i]);
}

extern "C" void kernel_launch(void* const* d_in, const int* in_sizes, int n_in,
                              void* d_out, int out_size, void* d_ws, size_t ws_size,
                              hipStream_t stream) {
  const float* X      = (const float*)d_in[0];
  const int*   ei     = (const int*)d_in[1];
  const float* pos    = (const float*)d_in[3];
  const float* W1     = (const float*)d_in[4];
  const float* a_src1 = (const float*)d_in[5];
  const float* a_dst1 = (const float*)d_in[6];
  const float* b1     = (const float*)d_in[7];
  const float* W2     = (const float*)d_in[8];
  const float* a_src2 = (const float*)d_in[9];
  const float* a_dst2 = (const float*)d_in[10];
  const float* b2     = (const float*)d_in[11];
  const float* bn1_g  = (const float*)d_in[12];
  const float* bn1_b  = (const float*)d_in[13];
  const float* bn2_g  = (const float*)d_in[14];
  const float* bn2_b  = (const float*)d_in[15];
  const float* out_W  = (const float*)d_in[18];
  const float* out_b  = (const float*)d_in[19];
  float* out = (float*)d_out;

  float* ws = (float*)d_ws;
  size_t o = 0;
  float* xl    = ws + o; o += (size_t)N_NODES * 512;   // 41 MB (GEMM out, both layers)
  float* aggA  = ws + o; o += (size_t)N_NODES * 512;   // 41 MB (h1 post-BN fp32, residual)
  float* aggB  = ws + o; o += (size_t)N_NODES * 512;   // 41 MB (layer2 agg)
  float* alS   = ws + o; o += (size_t)N_NODES * 4;
  float* alD   = ws + o; o += (size_t)N_NODES * 4;
  float* stats = ws + o; o += 2048;
  unsigned short* xbf  = (unsigned short*)(ws + o); o += (size_t)N_NODES * 64;   // 5.1 MB bf16
  unsigned short* hbf  = (unsigned short*)(ws + o); o += (size_t)N_NODES * 256;  // 20.5 MB bf16
  unsigned short* W1t  = (unsigned short*)(ws + o); o += 128 * 512 / 2;
  unsigned short* W2t  = (unsigned short*)(ws + o); o += 512 * 512 / 2;
  unsigned short* oWt  = (unsigned short*)(ws + o); o += 512 * 256 / 2;
  int* ip = (int*)(ws + o);
  int* counts    = ip; ip += N_NODES;
  int* row_start = ip; ip += N_NODES + 1;
  int* wcur      = ip; ip += N_NODES;
  int* srcs      = ip; ip += ETOT;
  // h2 bf16 aliases xl (xl dead after layer-2 k_agg)
  unsigned short* h2bf = (unsigned short*)xl;

  // CSR by dst (self loops included) + input prep
  k_init   <<<(N_NODES + 255) / 256, 256, 0, stream>>>(counts, stats);
  k_hist   <<<(N_EDGES + 255) / 256, 256, 0, stream>>>(ei, counts);
  k_scan   <<<1, 1024, 0, stream>>>(counts, row_start);
  k_self   <<<(N_NODES + 255) / 256, 256, 0, stream>>>(row_start, wcur, srcs);
  k_scatter<<<(N_EDGES + 255) / 256, 256, 0, stream>>>(ei, wcur, srcs);
  k_concat <<<(N_NODES * 128 + 255) / 256, 256, 0, stream>>>(X, pos, xbf);
  k_prep_w <<<(512 * 512 + 255) / 256, 256, 0, stream>>>(W1, W2, out_W, W1t, W2t, oWt);

  dim3 gemm_blk(256);
  // ---- layer 1 ----
  { dim3 g(512 / 128, (N_NODES + 127) / 128);
    k_mgemm<<<g, gemm_blk, 0, stream>>>(xbf, W1t, nullptr, xl, N_NODES, 512, 128); }
  k_al  <<<N_NODES, 512, 0, stream>>>(xl, a_src1, a_dst1, alS, alD);
  k_agg <<<N_NODES, 512, 0, stream>>>(xl, alS, alD, row_start, srcs, b1, aggA);
  k_stats<<<(N_NODES + 63) / 64, 512, 0, stream>>>(aggA, stats);
  k_bn_act<<<(N_NODES * 512 + 255) / 256, 256, 0, stream>>>(aggA, hbf, stats, bn1_g, bn1_b);
  // ---- layer 2 ----
  { dim3 g(512 / 128, (N_NODES + 127) / 128);
    k_mgemm<<<g, gemm_blk, 0, stream>>>(hbf, W2t, nullptr, xl, N_NODES, 512, 512); }
  k_al  <<<N_NODES, 512, 0, stream>>>(xl, a_src2, a_dst2, alS, alD);
  k_agg <<<N_NODES, 512, 0, stream>>>(xl, alS, alD, row_start, srcs, b2, aggB);
  k_stats<<<(N_NODES + 63) / 64, 512, 0, stream>>>(aggB, stats + 1024);
  k_bn_act_res<<<(N_NODES * 512 + 255) / 256, 256, 0, stream>>>(aggB, aggA, h2bf, stats + 1024, bn2_g, bn2_b);
  // ---- output projection ----
  { dim3 g(256 / 128, (N_NODES + 127) / 128);
    k_mgemm<<<g, gemm_blk, 0, stream>>>(h2bf, oWt, out_b, out, N_NODES, 256, 512); }
}

// Round 3
// 471.345 us; speedup vs baseline: 1.7787x; 1.3805x over previous
//
#include <hip/hip_runtime.h>
#include <hip/hip_bf16.h>
#include <math.h>

#define N_NODES 20000
#define N_EDGES 320000
#define F_IN    127
#define ETOT    (N_EDGES + N_NODES)

typedef __attribute__((ext_vector_type(8))) short short8;
typedef __attribute__((ext_vector_type(4))) float f32x4;

__device__ inline unsigned short f2bf(float f) {
  union { float f; unsigned int u; } v; v.f = f;
  unsigned int u = v.u;
  unsigned int r = (u + 0x7fffu + ((u >> 16) & 1u)) >> 16;
  return (unsigned short)r;
}
__device__ inline float bf2f(unsigned short b) {
  union { unsigned int u; float f; } v; v.u = ((unsigned int)b) << 16;
  return v.f;
}

// ---------------- CSR build ----------------
__global__ void k_init(int* __restrict__ counts, float* __restrict__ stats) {
  int i = blockIdx.x * blockDim.x + threadIdx.x;
  if (i < N_NODES) counts[i] = 1;   // self loop pre-counted
  if (i < 2048) stats[i] = 0.f;
}

__global__ void k_hist(const int* __restrict__ ei, int* __restrict__ counts) {
  int e = blockIdx.x * blockDim.x + threadIdx.x;
  if (e < N_EDGES) atomicAdd(&counts[ei[N_EDGES + e]], 1);
}

__global__ __launch_bounds__(1024) void k_scan(const int* __restrict__ counts,
                                               int* __restrict__ row_start) {
  __shared__ int part[1024];
  const int per = (N_NODES + 1023) / 1024;
  int t = threadIdx.x;
  int base = t * per;
  int s = 0;
  for (int i = 0; i < per; ++i) {
    int idx = base + i;
    if (idx < N_NODES) s += counts[idx];
  }
  part[t] = s;
  __syncthreads();
  for (int off = 1; off < 1024; off <<= 1) {
    int v = (t >= off) ? part[t - off] : 0;
    __syncthreads();
    part[t] += v;
    __syncthreads();
  }
  int run = part[t] - s;
  for (int i = 0; i < per; ++i) {
    int idx = base + i;
    if (idx < N_NODES) { row_start[idx] = run; run += counts[idx]; }
  }
  if (t == 1023) row_start[N_NODES] = part[1023];
}

__global__ void k_self(const int* __restrict__ row_start, int* __restrict__ wcur,
                       int* __restrict__ srcs) {
  int i = blockIdx.x * blockDim.x + threadIdx.x;
  if (i < N_NODES) { int p = row_start[i]; srcs[p] = i; wcur[i] = p + 1; }
}

__global__ void k_scatter(const int* __restrict__ ei, int* __restrict__ wcur,
                          int* __restrict__ srcs) {
  int e = blockIdx.x * blockDim.x + threadIdx.x;
  if (e < N_EDGES) {
    int s = ei[e], d = ei[N_EDGES + e];
    int p = atomicAdd(&wcur[d], 1);
    srcs[p] = s;
  }
}

// ---------------- concat x = [X | pos_emb] -> bf16 ----------------
__global__ void k_concat(const float* __restrict__ X, const float* __restrict__ pos,
                         unsigned short* __restrict__ xbf) {
  int i = blockIdx.x * blockDim.x + threadIdx.x;
  if (i >= N_NODES * 128) return;
  int n = i >> 7, k = i & 127;
  xbf[i] = f2bf((k < F_IN) ? X[n * F_IN + k] : pos[n]);
}

// ---------------- weights cast + transpose (bf16, B^T layout) ----------------
__global__ void k_prep_w(const float* __restrict__ W1, const float* __restrict__ W2,
                         const float* __restrict__ oW,
                         unsigned short* __restrict__ W1t, unsigned short* __restrict__ W2t,
                         unsigned short* __restrict__ oWt) {
  int i = blockIdx.x * blockDim.x + threadIdx.x;
  if (i < 128 * 512) { int r = i >> 9, c = i & 511; W1t[c * 128 + r] = f2bf(W1[i]); }
  if (i < 512 * 512) { int r = i >> 9, c = i & 511; W2t[c * 512 + r] = f2bf(W2[i]); }
  if (i < 512 * 256) { int r = i >> 8, c = i & 255; oWt[c * 512 + r] = f2bf(oW[i]); }
}

// ---------------- bf16 MFMA GEMM: C = A[M,K] @ Bt[Nc,K]^T (+bias) ----------------
// 128x128 tile, 256 thr (4 waves, 2x2), each wave 64x64 = 4x4 MFMA 16x16x32.
// Writes fp32 (Cf) or bf16 (Cbf) — exactly one non-null.
__global__ __launch_bounds__(256) void k_mgemm(
    const unsigned short* __restrict__ A, const unsigned short* __restrict__ Bt,
    const float* __restrict__ bias, float* __restrict__ Cf,
    unsigned short* __restrict__ Cbf, int M, int Nc, int K)
{
  __shared__ unsigned short As[128 * 32];
  __shared__ unsigned short Bs[128 * 32];
  int t = threadIdx.x;
  int w = t >> 6, l = t & 63;
  int wr = w >> 1, wc = w & 1;
  int lane15 = l & 15, kq = l >> 4;
  int m0 = blockIdx.y * 128, n0 = blockIdx.x * 128;
  f32x4 acc[4][4] = {};

  int cA = 2 * w;
  int rowA0 = 16 * cA + (l >> 2);
  int koff = (l & 3) * 8;

  for (int k0 = 0; k0 < K; k0 += 32) {
    __syncthreads();
#pragma unroll
    for (int cc = 0; cc < 2; ++cc) {
      int c = cA + cc;
      int row = rowA0 + 16 * cc;
      const unsigned short* g = A + (size_t)min(m0 + row, M - 1) * K + k0 + koff;
      __builtin_amdgcn_global_load_lds(
          (const __attribute__((address_space(1))) unsigned int*)g,
          (__attribute__((address_space(3))) unsigned int*)&As[c * 512], 16, 0, 0);
      const unsigned short* gb = Bt + (size_t)(n0 + row) * K + k0 + koff;
      __builtin_amdgcn_global_load_lds(
          (const __attribute__((address_space(1))) unsigned int*)gb,
          (__attribute__((address_space(3))) unsigned int*)&Bs[c * 512], 16, 0, 0);
    }
    __syncthreads();
    short8 a[4], b[4];
#pragma unroll
    for (int i = 0; i < 4; ++i)
      a[i] = *(const short8*)&As[(wr * 64 + i * 16 + lane15) * 32 + kq * 8];
#pragma unroll
    for (int j = 0; j < 4; ++j)
      b[j] = *(const short8*)&Bs[(wc * 64 + j * 16 + lane15) * 32 + kq * 8];
#pragma unroll
    for (int i = 0; i < 4; ++i)
#pragma unroll
      for (int j = 0; j < 4; ++j)
        acc[i][j] = __builtin_amdgcn_mfma_f32_16x16x32_bf16(a[i], b[j], acc[i][j], 0, 0, 0);
  }
  // epilogue: C/D layout col=lane&15, row=(lane>>4)*4+reg
#pragma unroll
  for (int i = 0; i < 4; ++i) {
#pragma unroll
    for (int j = 0; j < 4; ++j) {
      int col = n0 + wc * 64 + j * 16 + lane15;
      float bv = bias ? bias[col] : 0.f;
#pragma unroll
      for (int r = 0; r < 4; ++r) {
        int row = m0 + wr * 64 + i * 16 + kq * 4 + r;
        if (row < M) {
          float val = acc[i][j][r] + bv;
          if (Cbf) Cbf[(size_t)row * Nc + col] = f2bf(val);
          else     Cf[(size_t)row * Nc + col] = val;
        }
      }
    }
  }
}

// ---------------- attention logit vectors al_s/al_d [N,4], bf16 input ----------------
// 256 thr = 4 waves; wave h reduces channels [h*128, (h+1)*128) via ushort2 pairs.
__global__ __launch_bounds__(256) void k_al(
    const unsigned short* __restrict__ xlbf, const float* __restrict__ a_src,
    const float* __restrict__ a_dst, float* __restrict__ al_s, float* __restrict__ al_d)
{
  int n = blockIdx.x, t = threadIdx.x;
  int h = t >> 6, l = t & 63;
  int c0 = h * 128 + 2 * l;
  unsigned int v = *(const unsigned int*)&xlbf[(size_t)n * 512 + c0];
  float v0 = bf2f((unsigned short)(v & 0xffffu));
  float v1 = bf2f((unsigned short)(v >> 16));
  float ps = v0 * a_src[c0] + v1 * a_src[c0 + 1];
  float pd = v0 * a_dst[c0] + v1 * a_dst[c0 + 1];
#pragma unroll
  for (int off = 32; off; off >>= 1) { ps += __shfl_down(ps, off); pd += __shfl_down(pd, off); }
  if (l == 0) { al_s[n * 4 + h] = ps; al_d[n * 4 + h] = pd; }
}

// ---------------- GAT aggregate: wave-per-head, barrier-free ----------------
// Block 256 = 4 waves; wave h owns head h of node blockIdx.x.
__global__ __launch_bounds__(256) void k_agg(
    const unsigned short* __restrict__ xlbf, const float* __restrict__ al_s,
    const float* __restrict__ al_d, const int* __restrict__ row_start,
    const int* __restrict__ srcs, const float* __restrict__ bias,
    float* __restrict__ out)
{
  int n = blockIdx.x, t = threadIdx.x;
  int h = t >> 6, l = t & 63;
  __shared__ float2 s_af[4][64];   // wave-private (alpha, src) per chunk
  int rs = row_start[n], deg = row_start[n + 1] - rs;
  float ald = al_d[n * 4 + h];

  // online softmax (max + scaled denom), lane-strided over edges
  float lm = -1e30f, ls = 0.f;
  for (int i = l; i < deg; i += 64) {
    int s = srcs[rs + i];
    float lg = al_s[s * 4 + h] + ald;
    lg = (lg >= 0.f) ? lg : 0.2f * lg;
    if (lg > lm) { ls = ls * __expf(lm - lg) + 1.f; lm = lg; }
    else         { ls += __expf(lg - lm); }
  }
#pragma unroll
  for (int off = 32; off; off >>= 1) {
    float om = __shfl_xor(lm, off);
    float os = __shfl_xor(ls, off);
    float M = fmaxf(lm, om);
    ls = ls * __expf(lm - M) + os * __expf(om - M);
    lm = M;
  }
  float rinv = 1.f / (ls + 1e-16f);

  float acc0 = 0.f, acc1 = 0.f;
  const unsigned short* xp = xlbf + h * 128 + 2 * l;
  for (int c0 = 0; c0 < deg; c0 += 64) {
    int csz = min(64, deg - c0);
    if (l < csz) {
      int s = srcs[rs + c0 + l];
      float lg = al_s[s * 4 + h] + ald;
      lg = (lg >= 0.f) ? lg : 0.2f * lg;
      float a = __expf(lg - lm) * rinv;
      s_af[h][l] = make_float2(a, __int_as_float(s));
    }
    // wave-private LDS region; intra-wave program order + compiler lgkmcnt
#pragma unroll 4
    for (int e = 0; e < csz; ++e) {
      float2 af = s_af[h][e];
      int s = __float_as_int(af.y);
      unsigned int v = *(const unsigned int*)(xp + (size_t)s * 512);
      acc0 = fmaf(bf2f((unsigned short)(v & 0xffffu)), af.x, acc0);
      acc1 = fmaf(bf2f((unsigned short)(v >> 16)),     af.x, acc1);
    }
  }
  int c = h * 128 + 2 * l;
  float2 o = make_float2(acc0 + bias[c], acc1 + bias[c + 1]);
  *(float2*)&out[(size_t)n * 512 + c] = o;
}

// ---------------- column stats (sum, sumsq) ----------------
__global__ __launch_bounds__(512) void k_stats(const float* __restrict__ hdat,
                                               float* __restrict__ sums) {
  int t = threadIdx.x;
  int r0 = blockIdx.x * 64;
  int r1 = min(r0 + 64, N_NODES);
  float s = 0.f, q = 0.f;
  for (int r = r0; r < r1; ++r) {
    float v = hdat[(size_t)r * 512 + t];
    s += v; q = fmaf(v, v, q);
  }
  atomicAdd(&sums[t], s);
  atomicAdd(&sums[512 + t], q);
}

// ---------------- BN + LeakyReLU(0.01); fp32 in-place + bf16 copy ----------------
__global__ void k_bn_act(float* __restrict__ hdat, unsigned short* __restrict__ hbf,
                         const float* __restrict__ stats,
                         const float* __restrict__ g, const float* __restrict__ b) {
  int i = blockIdx.x * blockDim.x + threadIdx.x;
  if (i >= N_NODES * 512) return;
  int c = i & 511;
  const float invN = 1.f / N_NODES;
  float mu = stats[c] * invN;
  float var = stats[512 + c] * invN - mu * mu;
  float y = (hdat[i] - mu) * rsqrtf(var + 1e-5f) * g[c] + b[c];
  y = (y >= 0.f) ? y : 0.01f * y;
  hdat[i] = y;
  hbf[i] = f2bf(y);
}

// BN + act + residual -> bf16 only (feeds final projection)
__global__ void k_bn_act_res(const float* __restrict__ hdat, const float* __restrict__ hprev,
                             unsigned short* __restrict__ hbf,
                             const float* __restrict__ stats,
                             const float* __restrict__ g, const float* __restrict__ b) {
  int i = blockIdx.x * blockDim.x + threadIdx.x;
  if (i >= N_NODES * 512) return;
  int c = i & 511;
  const float invN = 1.f / N_NODES;
  float mu = stats[c] * invN;
  float var = stats[512 + c] * invN - mu * mu;
  float y = (hdat[i] - mu) * rsqrtf(var + 1e-5f) * g[c] + b[c];
  y = (y >= 0.f) ? y : 0.01f * y;
  hbf[i] = f2bf(y + hprev[i]);
}

extern "C" void kernel_launch(void* const* d_in, const int* in_sizes, int n_in,
                              void* d_out, int out_size, void* d_ws, size_t ws_size,
                              hipStream_t stream) {
  const float* X      = (const float*)d_in[0];
  const int*   ei     = (const int*)d_in[1];
  const float* pos    = (const float*)d_in[3];
  const float* W1     = (const float*)d_in[4];
  const float* a_src1 = (const float*)d_in[5];
  const float* a_dst1 = (const float*)d_in[6];
  const float* b1     = (const float*)d_in[7];
  const float* W2     = (const float*)d_in[8];
  const float* a_src2 = (const float*)d_in[9];
  const float* a_dst2 = (const float*)d_in[10];
  const float* b2     = (const float*)d_in[11];
  const float* bn1_g  = (const float*)d_in[12];
  const float* bn1_b  = (const float*)d_in[13];
  const float* bn2_g  = (const float*)d_in[14];
  const float* bn2_b  = (const float*)d_in[15];
  const float* out_W  = (const float*)d_in[18];
  const float* out_b  = (const float*)d_in[19];
  float* out = (float*)d_out;

  float* ws = (float*)d_ws;
  size_t o = 0;
  float* aggA  = ws + o; o += (size_t)N_NODES * 512;   // 41 MB (h1 post-BN fp32, residual)
  float* aggB  = ws + o; o += (size_t)N_NODES * 512;   // 41 MB (layer2 agg)
  float* alS   = ws + o; o += (size_t)N_NODES * 4;
  float* alD   = ws + o; o += (size_t)N_NODES * 4;
  float* stats = ws + o; o += 2048;
  unsigned short* xlbf = (unsigned short*)(ws + o); o += (size_t)N_NODES * 256;  // 20.5 MB (GEMM out, both layers)
  unsigned short* xbf  = (unsigned short*)(ws + o); o += (size_t)N_NODES * 64;   // 5.1 MB input bf16
  unsigned short* hbf  = (unsigned short*)(ws + o); o += (size_t)N_NODES * 256;  // h1 bf16
  unsigned short* W1t  = (unsigned short*)(ws + o); o += 128 * 512 / 2;
  unsigned short* W2t  = (unsigned short*)(ws + o); o += 512 * 512 / 2;
  unsigned short* oWt  = (unsigned short*)(ws + o); o += 512 * 256 / 2;
  int* ip = (int*)(ws + o);
  int* counts    = ip; ip += N_NODES;
  int* row_start = ip; ip += N_NODES + 1;
  int* wcur      = ip; ip += N_NODES;
  int* srcs      = ip; ip += ETOT;
  // h2 bf16 aliases xlbf (dead after layer-2 k_al/k_agg)
  unsigned short* h2bf = xlbf;

  // CSR by dst (self loops included) + input prep
  k_init   <<<(N_NODES + 255) / 256, 256, 0, stream>>>(counts, stats);
  k_hist   <<<(N_EDGES + 255) / 256, 256, 0, stream>>>(ei, counts);
  k_scan   <<<1, 1024, 0, stream>>>(counts, row_start);
  k_self   <<<(N_NODES + 255) / 256, 256, 0, stream>>>(row_start, wcur, srcs);
  k_scatter<<<(N_EDGES + 255) / 256, 256, 0, stream>>>(ei, wcur, srcs);
  k_concat <<<(N_NODES * 128 + 255) / 256, 256, 0, stream>>>(X, pos, xbf);
  k_prep_w <<<(512 * 512 + 255) / 256, 256, 0, stream>>>(W1, W2, out_W, W1t, W2t, oWt);

  // ---- layer 1 ----
  { dim3 g(512 / 128, (N_NODES + 127) / 128);
    k_mgemm<<<g, 256, 0, stream>>>(xbf, W1t, nullptr, nullptr, xlbf, N_NODES, 512, 128); }
  k_al  <<<N_NODES, 256, 0, stream>>>(xlbf, a_src1, a_dst1, alS, alD);
  k_agg <<<N_NODES, 256, 0, stream>>>(xlbf, alS, alD, row_start, srcs, b1, aggA);
  k_stats<<<(N_NODES + 63) / 64, 512, 0, stream>>>(aggA, stats);
  k_bn_act<<<(N_NODES * 512 + 255) / 256, 256, 0, stream>>>(aggA, hbf, stats, bn1_g, bn1_b);
  // ---- layer 2 ----
  { dim3 g(512 / 128, (N_NODES + 127) / 128);
    k_mgemm<<<g, 256, 0, stream>>>(hbf, W2t, nullptr, nullptr, xlbf, N_NODES, 512, 512); }
  k_al  <<<N_NODES, 256, 0, stream>>>(xlbf, a_src2, a_dst2, alS, alD);
  k_agg <<<N_NODES, 256, 0, stream>>>(xlbf, alS, alD, row_start, srcs, b2, aggB);
  k_stats<<<(N_NODES + 63) / 64, 512, 0, stream>>>(aggB, stats + 1024);
  k_bn_act_res<<<(N_NODES * 512 + 255) / 256, 256, 0, stream>>>(aggB, aggA, h2bf, stats + 1024, bn2_g, bn2_b);
  // ---- output projection ----
  { dim3 g(256 / 128, (N_NODES + 127) / 128);
    k_mgemm<<<g, 256, 0, stream>>>(h2bf, oWt, out_b, out, nullptr, N_NODES, 256, 512); }
}

// Round 4
// 461.896 us; speedup vs baseline: 1.8151x; 1.0205x over previous
//
#include <hip/hip_runtime.h>
#include <hip/hip_bf16.h>
#include <math.h>

#define N_NODES 20000
#define N_EDGES 320000
#define F_IN    127
#define ETOT    (N_EDGES + N_NODES)

typedef __attribute__((ext_vector_type(8))) short short8;
typedef __attribute__((ext_vector_type(4))) float f32x4;

__device__ inline unsigned short f2bf(float f) {
  union { float f; unsigned int u; } v; v.f = f;
  unsigned int u = v.u;
  unsigned int r = (u + 0x7fffu + ((u >> 16) & 1u)) >> 16;
  return (unsigned short)r;
}
__device__ inline float bf2f(unsigned short b) {
  union { unsigned int u; float f; } v; v.u = ((unsigned int)b) << 16;
  return v.f;
}
__device__ inline float bflo(unsigned int v) {
  union { unsigned int u; float f; } x; x.u = v << 16; return x.f;
}
__device__ inline float bfhi(unsigned int v) {
  union { unsigned int u; float f; } x; x.u = v & 0xffff0000u; return x.f;
}

// ---------------- CSR build ----------------
__global__ void k_init(int* __restrict__ counts, float* __restrict__ stats) {
  int i = blockIdx.x * blockDim.x + threadIdx.x;
  if (i < N_NODES) counts[i] = 1;   // self loop pre-counted
  if (i < 2048) stats[i] = 0.f;
}

__global__ void k_hist(const int* __restrict__ ei, int* __restrict__ counts) {
  int e = blockIdx.x * blockDim.x + threadIdx.x;
  if (e < N_EDGES) atomicAdd(&counts[ei[N_EDGES + e]], 1);
}

// scan + self-loop placement + write-cursor init (merged)
__global__ __launch_bounds__(1024) void k_scan(const int* __restrict__ counts,
                                               int* __restrict__ row_start,
                                               int* __restrict__ wcur,
                                               int* __restrict__ srcs) {
  __shared__ int part[1024];
  const int per = (N_NODES + 1023) / 1024;
  int t = threadIdx.x;
  int base = t * per;
  int s = 0;
  for (int i = 0; i < per; ++i) {
    int idx = base + i;
    if (idx < N_NODES) s += counts[idx];
  }
  part[t] = s;
  __syncthreads();
  for (int off = 1; off < 1024; off <<= 1) {
    int v = (t >= off) ? part[t - off] : 0;
    __syncthreads();
    part[t] += v;
    __syncthreads();
  }
  int run = part[t] - s;
  for (int i = 0; i < per; ++i) {
    int idx = base + i;
    if (idx < N_NODES) {
      row_start[idx] = run;
      srcs[run] = idx;          // self loop at slot 0 of each row
      wcur[idx] = run + 1;
      run += counts[idx];
    }
  }
  if (t == 1023) row_start[N_NODES] = part[1023];
}

__global__ void k_scatter(const int* __restrict__ ei, int* __restrict__ wcur,
                          int* __restrict__ srcs) {
  int e = blockIdx.x * blockDim.x + threadIdx.x;
  if (e < N_EDGES) {
    int s = ei[e], d = ei[N_EDGES + e];
    int p = atomicAdd(&wcur[d], 1);
    srcs[p] = s;
  }
}

// ---------------- input concat + weight cast/transpose (merged) ----------------
__global__ void k_prep(const float* __restrict__ X, const float* __restrict__ pos,
                       unsigned short* __restrict__ xbf,
                       const float* __restrict__ W1, const float* __restrict__ W2,
                       const float* __restrict__ oW,
                       unsigned short* __restrict__ W1t, unsigned short* __restrict__ W2t,
                       unsigned short* __restrict__ oWt) {
  int i = blockIdx.x * blockDim.x + threadIdx.x;
  if (i < N_NODES * 128) { int n = i >> 7, k = i & 127; xbf[i] = f2bf((k < F_IN) ? X[n * F_IN + k] : pos[n]); }
  if (i < 128 * 512) { int r = i >> 9, c = i & 511; W1t[c * 128 + r] = f2bf(W1[i]); }
  if (i < 512 * 512) { int r = i >> 9, c = i & 511; W2t[c * 512 + r] = f2bf(W2[i]); }
  if (i < 512 * 256) { int r = i >> 8, c = i & 255; oWt[c * 512 + r] = f2bf(oW[i]); }
}

// ---------------- bf16 MFMA GEMM: C = A[M,K] @ Bt[Nc,K]^T (+bias) ----------------
// 128x128 tile, 256 thr (4 waves, 2x2), each wave 64x64 = 4x4 MFMA 16x16x32.
__global__ __launch_bounds__(256) void k_mgemm(
    const unsigned short* __restrict__ A, const unsigned short* __restrict__ Bt,
    const float* __restrict__ bias, float* __restrict__ Cf,
    unsigned short* __restrict__ Cbf, int M, int Nc, int K)
{
  __shared__ unsigned short As[128 * 32];
  __shared__ unsigned short Bs[128 * 32];
  int t = threadIdx.x;
  int w = t >> 6, l = t & 63;
  int wr = w >> 1, wc = w & 1;
  int lane15 = l & 15, kq = l >> 4;
  int m0 = blockIdx.y * 128, n0 = blockIdx.x * 128;
  f32x4 acc[4][4] = {};

  int cA = 2 * w;
  int rowA0 = 16 * cA + (l >> 2);
  int koff = (l & 3) * 8;

  for (int k0 = 0; k0 < K; k0 += 32) {
    __syncthreads();
#pragma unroll
    for (int cc = 0; cc < 2; ++cc) {
      int c = cA + cc;
      int row = rowA0 + 16 * cc;
      const unsigned short* g = A + (size_t)min(m0 + row, M - 1) * K + k0 + koff;
      __builtin_amdgcn_global_load_lds(
          (const __attribute__((address_space(1))) unsigned int*)g,
          (__attribute__((address_space(3))) unsigned int*)&As[c * 512], 16, 0, 0);
      const unsigned short* gb = Bt + (size_t)(n0 + row) * K + k0 + koff;
      __builtin_amdgcn_global_load_lds(
          (const __attribute__((address_space(1))) unsigned int*)gb,
          (__attribute__((address_space(3))) unsigned int*)&Bs[c * 512], 16, 0, 0);
    }
    __syncthreads();
    short8 a[4], b[4];
#pragma unroll
    for (int i = 0; i < 4; ++i)
      a[i] = *(const short8*)&As[(wr * 64 + i * 16 + lane15) * 32 + kq * 8];
#pragma unroll
    for (int j = 0; j < 4; ++j)
      b[j] = *(const short8*)&Bs[(wc * 64 + j * 16 + lane15) * 32 + kq * 8];
#pragma unroll
    for (int i = 0; i < 4; ++i)
#pragma unroll
      for (int j = 0; j < 4; ++j)
        acc[i][j] = __builtin_amdgcn_mfma_f32_16x16x32_bf16(a[i], b[j], acc[i][j], 0, 0, 0);
  }
  // epilogue: C/D layout col=lane&15, row=(lane>>4)*4+reg
#pragma unroll
  for (int i = 0; i < 4; ++i) {
#pragma unroll
    for (int j = 0; j < 4; ++j) {
      int col = n0 + wc * 64 + j * 16 + lane15;
      float bv = bias ? bias[col] : 0.f;
#pragma unroll
      for (int r = 0; r < 4; ++r) {
        int row = m0 + wr * 64 + i * 16 + kq * 4 + r;
        if (row < M) {
          float val = acc[i][j][r] + bv;
          if (Cbf) Cbf[(size_t)row * Nc + col] = f2bf(val);
          else     Cf[(size_t)row * Nc + col] = val;
        }
      }
    }
  }
}

// ---------------- attention logit vectors al_s/al_d [N,4], bf16 input ----------------
__global__ __launch_bounds__(256) void k_al(
    const unsigned short* __restrict__ xlbf, const float* __restrict__ a_src,
    const float* __restrict__ a_dst, float* __restrict__ al_s, float* __restrict__ al_d)
{
  int n = blockIdx.x, t = threadIdx.x;
  int h = t >> 6, l = t & 63;
  int c0 = h * 128 + 2 * l;
  unsigned int v = *(const unsigned int*)&xlbf[(size_t)n * 512 + c0];
  float v0 = bflo(v), v1 = bfhi(v);
  float ps = v0 * a_src[c0] + v1 * a_src[c0 + 1];
  float pd = v0 * a_dst[c0] + v1 * a_dst[c0 + 1];
#pragma unroll
  for (int off = 32; off; off >>= 1) { ps += __shfl_down(ps, off); pd += __shfl_down(pd, off); }
  if (l == 0) { al_s[n * 4 + h] = ps; al_d[n * 4 + h] = pd; }
}

// ---------------- GAT aggregate: wave-per-node, 16B/lane gathers ----------------
// Block 256 = 4 waves; wave w owns node blockIdx.x*4+w. Lane l: channels 8l..8l+7
// (head = l>>4). Softmax per-head in 16-lane subgroups.
__global__ __launch_bounds__(256) void k_agg(
    const unsigned short* __restrict__ xlbf, const float* __restrict__ al_s,
    const float* __restrict__ al_d, const int* __restrict__ row_start,
    const int* __restrict__ srcs, const float* __restrict__ bias,
    float* __restrict__ out)
{
  int w = threadIdx.x >> 6, l = threadIdx.x & 63;
  int n = blockIdx.x * 4 + w;
  if (n >= N_NODES) return;
  int h = l >> 4;          // head owning channels 8l..8l+7
  int g = l & 15;          // lane within head subgroup
  __shared__ float s_al[4][64][4];   // [wave][edge][head]
  __shared__ int   s_src[4][64];
  __shared__ float s_m[4][4], s_r[4][4];

  int rs = row_start[n];
  int deg = row_start[n + 1] - rs;
  float ald_h = al_d[n * 4 + h];

  // phase A: online softmax per head, 16-lane subgroup strided over edges
  float lm = -1e30f, ls = 0.f;
  for (int i = g; i < deg; i += 16) {
    int s = srcs[rs + i];
    float lg = al_s[s * 4 + h] + ald_h;
    lg = (lg >= 0.f) ? lg : 0.2f * lg;
    if (lg > lm) { ls = ls * __expf(lm - lg) + 1.f; lm = lg; }
    else         { ls += __expf(lg - lm); }
  }
#pragma unroll
  for (int off = 8; off; off >>= 1) {
    float om = __shfl_xor(lm, off);
    float os = __shfl_xor(ls, off);
    float M = fmaxf(lm, om);
    ls = ls * __expf(lm - M) + os * __expf(om - M);
    lm = M;
  }
  if (g == 0) {
    s_m[w][h] = lm;
    s_r[w][h] = 1.f / (ls + 1e-16f);
  }
  // wave-synchronous: LDS write->read within one wave is program-ordered

  float acc[8] = {};
  const unsigned short* xp = xlbf + 8 * l;
  float4 ad4 = *(const float4*)&al_d[n * 4];
  for (int c0 = 0; c0 < deg; c0 += 64) {
    int csz = min(64, deg - c0);
    if (l < csz) {
      int s = srcs[rs + c0 + l];
      s_src[w][l] = s;
      float4 as4 = *(const float4*)&al_s[(size_t)s * 4];
      float lg0 = as4.x + ad4.x; lg0 = (lg0 >= 0.f) ? lg0 : 0.2f * lg0;
      float lg1 = as4.y + ad4.y; lg1 = (lg1 >= 0.f) ? lg1 : 0.2f * lg1;
      float lg2 = as4.z + ad4.z; lg2 = (lg2 >= 0.f) ? lg2 : 0.2f * lg2;
      float lg3 = as4.w + ad4.w; lg3 = (lg3 >= 0.f) ? lg3 : 0.2f * lg3;
      s_al[w][l][0] = __expf(lg0 - s_m[w][0]) * s_r[w][0];
      s_al[w][l][1] = __expf(lg1 - s_m[w][1]) * s_r[w][1];
      s_al[w][l][2] = __expf(lg2 - s_m[w][2]) * s_r[w][2];
      s_al[w][l][3] = __expf(lg3 - s_m[w][3]) * s_r[w][3];
    }
#pragma unroll 4
    for (int e = 0; e < csz; ++e) {
      float a = s_al[w][e][h];
      int s = s_src[w][e];
      uint4 v = *(const uint4*)(xp + (size_t)s * 512);
      acc[0] = fmaf(bflo(v.x), a, acc[0]);
      acc[1] = fmaf(bfhi(v.x), a, acc[1]);
      acc[2] = fmaf(bflo(v.y), a, acc[2]);
      acc[3] = fmaf(bfhi(v.y), a, acc[3]);
      acc[4] = fmaf(bflo(v.z), a, acc[4]);
      acc[5] = fmaf(bfhi(v.z), a, acc[5]);
      acc[6] = fmaf(bflo(v.w), a, acc[6]);
      acc[7] = fmaf(bfhi(v.w), a, acc[7]);
    }
  }
  int c = 8 * l;
  float* op = out + (size_t)n * 512 + c;
  float4 o0 = make_float4(acc[0] + bias[c],     acc[1] * 0.5f + acc[1] * 0.5f + bias[c + 1],
                          acc[2] + bias[c + 2], acc[3] + bias[c + 3]);
  // (note: acc[1]*0.5+acc[1]*0.5 == acc[1]; phrasing avoids nothing — keep simple)
  o0.y = acc[1] + bias[c + 1];
  float4 o1 = make_float4(acc[4] + bias[c + 4], acc[5] + bias[c + 5],
                          acc[6] + bias[c + 6], acc[7] + bias[c + 7]);
  *(float4*)op = o0;
  *(float4*)(op + 4) = o1;
}

// ---------------- column stats (sum, sumsq) ----------------
__global__ __launch_bounds__(512) void k_stats(const float* __restrict__ hdat,
                                               float* __restrict__ sums) {
  int t = threadIdx.x;
  int r0 = blockIdx.x * 64;
  int r1 = min(r0 + 64, N_NODES);
  float s = 0.f, q = 0.f;
  for (int r = r0; r < r1; ++r) {
    float v = hdat[(size_t)r * 512 + t];
    s += v; q = fmaf(v, v, q);
  }
  atomicAdd(&sums[t], s);
  atomicAdd(&sums[512 + t], q);
}

// ---------------- BN + LeakyReLU(0.01) -> bf16 ----------------
__global__ void k_bn_act(const float* __restrict__ hdat, unsigned short* __restrict__ hbf,
                         const float* __restrict__ stats,
                         const float* __restrict__ g, const float* __restrict__ b) {
  int i = blockIdx.x * blockDim.x + threadIdx.x;
  if (i >= N_NODES * 512) return;
  int c = i & 511;
  const float invN = 1.f / N_NODES;
  float mu = stats[c] * invN;
  float var = stats[512 + c] * invN - mu * mu;
  float y = (hdat[i] - mu) * rsqrtf(var + 1e-5f) * g[c] + b[c];
  y = (y >= 0.f) ? y : 0.01f * y;
  hbf[i] = f2bf(y);
}

// BN + act + residual (bf16 h1) -> bf16
__global__ void k_bn_act_res(const float* __restrict__ hdat, const unsigned short* __restrict__ hprev,
                             unsigned short* __restrict__ hbf,
                             const float* __restrict__ stats,
                             const float* __restrict__ g, const float* __restrict__ b) {
  int i = blockIdx.x * blockDim.x + threadIdx.x;
  if (i >= N_NODES * 512) return;
  int c = i & 511;
  const float invN = 1.f / N_NODES;
  float mu = stats[c] * invN;
  float var = stats[512 + c] * invN - mu * mu;
  float y = (hdat[i] - mu) * rsqrtf(var + 1e-5f) * g[c] + b[c];
  y = (y >= 0.f) ? y : 0.01f * y;
  hbf[i] = f2bf(y + bf2f(hprev[i]));
}

extern "C" void kernel_launch(void* const* d_in, const int* in_sizes, int n_in,
                              void* d_out, int out_size, void* d_ws, size_t ws_size,
                              hipStream_t stream) {
  const float* X      = (const float*)d_in[0];
  const int*   ei     = (const int*)d_in[1];
  const float* pos    = (const float*)d_in[3];
  const float* W1     = (const float*)d_in[4];
  const float* a_src1 = (const float*)d_in[5];
  const float* a_dst1 = (const float*)d_in[6];
  const float* b1     = (const float*)d_in[7];
  const float* W2     = (const float*)d_in[8];
  const float* a_src2 = (const float*)d_in[9];
  const float* a_dst2 = (const float*)d_in[10];
  const float* b2     = (const float*)d_in[11];
  const float* bn1_g  = (const float*)d_in[12];
  const float* bn1_b  = (const float*)d_in[13];
  const float* bn2_g  = (const float*)d_in[14];
  const float* bn2_b  = (const float*)d_in[15];
  const float* out_W  = (const float*)d_in[18];
  const float* out_b  = (const float*)d_in[19];
  float* out = (float*)d_out;

  float* ws = (float*)d_ws;
  size_t o = 0;
  float* agg   = ws + o; o += (size_t)N_NODES * 512;   // 41 MB fp32 (pre-BN, both layers)
  float* alS   = ws + o; o += (size_t)N_NODES * 4;
  float* alD   = ws + o; o += (size_t)N_NODES * 4;
  float* stats = ws + o; o += 2048;
  unsigned short* xlbf = (unsigned short*)(ws + o); o += (size_t)N_NODES * 256;  // GEMM out (both layers)
  unsigned short* xbf  = (unsigned short*)(ws + o); o += (size_t)N_NODES * 64;   // input bf16
  unsigned short* hbf  = (unsigned short*)(ws + o); o += (size_t)N_NODES * 256;  // h1 bf16 (GEMM2 in + residual)
  unsigned short* h2bf = (unsigned short*)(ws + o); o += (size_t)N_NODES * 256;  // h2 bf16 (out-proj in)
  unsigned short* W1t  = (unsigned short*)(ws + o); o += 128 * 512 / 2;
  unsigned short* W2t  = (unsigned short*)(ws + o); o += 512 * 512 / 2;
  unsigned short* oWt  = (unsigned short*)(ws + o); o += 512 * 256 / 2;
  int* ip = (int*)(ws + o);
  int* counts    = ip; ip += N_NODES;
  int* row_start = ip; ip += N_NODES + 1;
  int* wcur      = ip; ip += N_NODES;
  int* srcs      = ip; ip += ETOT;

  // CSR by dst (self loops included) + input prep
  k_init   <<<(N_NODES + 255) / 256, 256, 0, stream>>>(counts, stats);
  k_hist   <<<(N_EDGES + 255) / 256, 256, 0, stream>>>(ei, counts);
  k_scan   <<<1, 1024, 0, stream>>>(counts, row_start, wcur, srcs);
  k_scatter<<<(N_EDGES + 255) / 256, 256, 0, stream>>>(ei, wcur, srcs);
  k_prep   <<<(N_NODES * 128 + 255) / 256, 256, 0, stream>>>(X, pos, xbf, W1, W2, out_W, W1t, W2t, oWt);

  // ---- layer 1 ----
  { dim3 g(512 / 128, (N_NODES + 127) / 128);
    k_mgemm<<<g, 256, 0, stream>>>(xbf, W1t, nullptr, nullptr, xlbf, N_NODES, 512, 128); }
  k_al  <<<N_NODES, 256, 0, stream>>>(xlbf, a_src1, a_dst1, alS, alD);
  k_agg <<<(N_NODES + 3) / 4, 256, 0, stream>>>(xlbf, alS, alD, row_start, srcs, b1, agg);
  k_stats<<<(N_NODES + 63) / 64, 512, 0, stream>>>(agg, stats);
  k_bn_act<<<(N_NODES * 512 + 255) / 256, 256, 0, stream>>>(agg, hbf, stats, bn1_g, bn1_b);
  // ---- layer 2 ----
  { dim3 g(512 / 128, (N_NODES + 127) / 128);
    k_mgemm<<<g, 256, 0, stream>>>(hbf, W2t, nullptr, nullptr, xlbf, N_NODES, 512, 512); }
  k_al  <<<N_NODES, 256, 0, stream>>>(xlbf, a_src2, a_dst2, alS, alD);
  k_agg <<<(N_NODES + 3) / 4, 256, 0, stream>>>(xlbf, alS, alD, row_start, srcs, b2, agg);
  k_stats<<<(N_NODES + 63) / 64, 512, 0, stream>>>(agg, stats + 1024);
  k_bn_act_res<<<(N_NODES * 512 + 255) / 256, 256, 0, stream>>>(agg, hbf, h2bf, stats + 1024, bn2_g, bn2_b);
  // ---- output projection ----
  { dim3 g(256 / 128, (N_NODES + 127) / 128);
    k_mgemm<<<g, 256, 0, stream>>>(h2bf, oWt, out_b, out, nullptr, N_NODES, 256, 512); }
}